// Round 3
// baseline (266.988 us; speedup 1.0000x reference)
//
#include <hip/hip_runtime.h>

#define B_SZ 1024
#define D_SZ 128
#define KTERMS 8

// dot of a register-resident row (full unroll -> stays in VGPRs) with an
// LDS vector (all lanes read the same address -> broadcast, conflict-free)
__device__ inline float dot_regs(const float* r, const float* v) {
    float a0 = 0.f, a1 = 0.f, a2 = 0.f, a3 = 0.f;
#pragma unroll
    for (int j = 0; j < D_SZ; j += 8) {
        float4 v0 = *(const float4*)(v + j);
        float4 v1 = *(const float4*)(v + j + 4);
        a0 = fmaf(r[j + 0], v0.x, a0);
        a1 = fmaf(r[j + 1], v0.y, a1);
        a2 = fmaf(r[j + 2], v0.z, a2);
        a3 = fmaf(r[j + 3], v0.w, a3);
        a0 = fmaf(r[j + 4], v1.x, a0);
        a1 = fmaf(r[j + 5], v1.y, a1);
        a2 = fmaf(r[j + 6], v1.z, a2);
        a3 = fmaf(r[j + 7], v1.w, a3);
    }
    return (a0 + a1) + (a2 + a3);
}

// One block per batch element b.  All fp32 in / fp32 out.
// Math: t1+t2 = 2*t0+h  =>  alpha1 = h*A0 + h*s*W,  s = t0 + h/2
//       t2-t1 = h/sqrt(3) => alpha2 = h^2 * W  (scalar multiple of W!)
//       comm  = h^3 [A0, W]
//       Omega = h*A0 + h*s*W - (h^3/12)(A0 W - W A0)
//       y = expm(Omega) y0 via Taylor (||Omega|| < ~0.5, 8 terms -> ~1e-7)
//       Omega*v = h*(A0 v) + h*s*(W v) - (h^3/12)*(A0 (W v) - W (A0 v))
__global__ void __launch_bounds__(256, 2)
magnus_kernel(const float* __restrict__ t0p, const float* __restrict__ hp,
              const float* __restrict__ y0, const float* __restrict__ A0,
              const float* __restrict__ W, float* __restrict__ out)
{
    __shared__ __align__(16) float sv[D_SZ];
    __shared__ __align__(16) float su1[D_SZ];
    __shared__ __align__(16) float su2[D_SZ];
    __shared__ __align__(16) float su3[D_SZ];
    __shared__ __align__(16) float su4[D_SZ];

    const int b = blockIdx.x;
    const int tid = threadIdx.x;
    const float h = hp[0];
    const float tb = t0p[b];
    const float SQ3_6 = 0.28867513459481287f;  // sqrt(3)/6
    const float t1 = tb + (0.5f - SQ3_6) * h;
    const float t2 = tb + (0.5f + SQ3_6) * h;

    const size_t moff = (size_t)b * (D_SZ * D_SZ);
    const float4* A0v = (const float4*)(A0 + moff);
    const float4* Wv  = (const float4*)(W + moff);
    float4* o1 = (float4*)(out + (size_t)B_SZ * D_SZ + moff);
    float4* o2 = (float4*)(out + (size_t)B_SZ * D_SZ
                               + (size_t)B_SZ * D_SZ * D_SZ + moff);

    // ---- Phase 1: stream A0, W once (coalesced float4); emit A1, A2 (fp32) ----
#pragma unroll 4
    for (int it = 0; it < 16; ++it) {
        int i = it * 256 + tid;  // float4 chunk index, 0..4095
        float4 a = A0v[i];
        float4 w = Wv[i];
        float4 p1, p2;
        p1.x = fmaf(t1, w.x, a.x);
        p1.y = fmaf(t1, w.y, a.y);
        p1.z = fmaf(t1, w.z, a.z);
        p1.w = fmaf(t1, w.w, a.w);
        p2.x = fmaf(t2, w.x, a.x);
        p2.y = fmaf(t2, w.y, a.y);
        p2.z = fmaf(t2, w.z, a.z);
        p2.w = fmaf(t2, w.w, a.w);
        o1[i] = p1;
        o2[i] = p2;
    }

    // ---- Phase 2: each thread grabs its own matrix row into registers ----
    // threads 0..127: A0 row tid; threads 128..255: W row tid-128 (L2-hot).
    float r[D_SZ];
    {
        const float4* src = (tid < D_SZ)
            ? (const float4*)(A0 + moff + (size_t)tid * D_SZ)
            : (const float4*)(W + moff + (size_t)(tid - D_SZ) * D_SZ);
#pragma unroll
        for (int j = 0; j < D_SZ / 4; ++j) {
            float4 q = src[j];
            r[4 * j + 0] = q.x;
            r[4 * j + 1] = q.y;
            r[4 * j + 2] = q.z;
            r[4 * j + 3] = q.w;
        }
    }

    // ---- Phase 3: Taylor series y = sum_k Omega^k y0 / k! ----
    float yacc = 0.0f;
    if (tid < D_SZ) {
        float v = y0[(size_t)b * D_SZ + tid];
        sv[tid] = v;
        yacc = v;
    }
    __syncthreads();

    const float hs = h * (tb + 0.5f * h);           // h * s
    const float c3 = h * h * h * (1.0f / 12.0f);    // h^3 / 12

    for (int k = 1; k <= KTERMS; ++k) {
        // Round A: u1 = A0 v (tid<128) | u2 = W v (tid>=128)
        float accA = dot_regs(r, sv);
        if (tid < D_SZ) su1[tid] = accA; else su2[tid - D_SZ] = accA;
        __syncthreads();
        // Round B: u3 = A0 u2 (tid<128) | u4 = W u1 (tid>=128)
        const float* vb = (tid < D_SZ) ? su2 : su1;
        float accB = dot_regs(r, vb);
        if (tid < D_SZ) su3[tid] = accB; else su4[tid - D_SZ] = accB;
        __syncthreads();
        if (tid < D_SZ) {
            float wn = h * su1[tid] + hs * su2[tid] - c3 * (su3[tid] - su4[tid]);
            wn *= (1.0f / (float)k);
            yacc += wn;
            sv[tid] = wn;
        }
        __syncthreads();
    }

    if (tid < D_SZ) {
        out[(size_t)b * D_SZ + tid] = yacc;
    }
}

extern "C" void kernel_launch(void* const* d_in, const int* in_sizes, int n_in,
                              void* d_out, int out_size, void* d_ws, size_t ws_size,
                              hipStream_t stream) {
    const float* t0 = (const float*)d_in[0];
    const float* h  = (const float*)d_in[1];
    const float* y0 = (const float*)d_in[2];
    const float* A0 = (const float*)d_in[3];
    const float* W  = (const float*)d_in[4];
    float* out = (float*)d_out;
    magnus_kernel<<<B_SZ, 256, 0, stream>>>(t0, h, y0, A0, W, out);
}